// Round 2
// baseline (255.654 us; speedup 1.0000x reference)
//
#include <hip/hip_runtime.h>
#include <hip/hip_bf16.h>

#define B_SZ 16384
#define F_SZ 2048
#define D_SZ 256
#define E_SZ 8
#define GRID_G 528   // (sum_e ceil(count_e/64) <= 264) * 2 n-tiles; divisible by 8
#define XCHUNK (GRID_G / 8)

typedef __attribute__((ext_vector_type(8))) short bhalf8;
typedef __attribute__((ext_vector_type(4))) float fl4;

__device__ __forceinline__ short f2b(float f) {
  __hip_bfloat16 h = __float2bfloat16(f);
  union { __hip_bfloat16 h; short s; } u;
  u.h = h;
  return u.s;
}

// ---------------- bucket scatter ----------------
__global__ void k_scatter(const int* __restrict__ ids, int* __restrict__ counts,
                          int* __restrict__ perm) {
  __shared__ int lcnt[E_SZ], lbase[E_SZ];
  int t = threadIdx.x;
  if (t < E_SZ) lcnt[t] = 0;
  __syncthreads();
  int b = blockIdx.x * 256 + t;
  int e = ids[b];
  int p = atomicAdd(&lcnt[e], 1);
  __syncthreads();
  if (t < E_SZ) lbase[t] = atomicAdd(&counts[t], lcnt[t]);
  __syncthreads();
  perm[e * B_SZ + lbase[e] + p] = b;
}

// ---------------- W transpose+cast: Wt[e][d][f] = bf16(W[e][f][d]) ----------------
__global__ void k_transpose(const float* __restrict__ W, __hip_bfloat16* __restrict__ Wt) {
  __shared__ float tile[64][65];
  int e = blockIdx.z;
  int f0 = blockIdx.x * 64;
  int d0 = blockIdx.y * 64;
  int t = threadIdx.x;
  const float* src = W + ((size_t)e * F_SZ + f0) * D_SZ + d0;
  int fr = t >> 2, c0 = t & 3;
#pragma unroll
  for (int c = c0; c < 16; c += 4) {
    float4 v = *(const float4*)(src + (size_t)fr * D_SZ + c * 4);
    tile[fr][c * 4 + 0] = v.x;
    tile[fr][c * 4 + 1] = v.y;
    tile[fr][c * 4 + 2] = v.z;
    tile[fr][c * 4 + 3] = v.w;
  }
  __syncthreads();
  int dr = t >> 2, cc = t & 3;
  union { unsigned short u[16]; bhalf8 v[2]; } pk;
#pragma unroll
  for (int k = 0; k < 16; ++k) pk.u[k] = (unsigned short)f2b(tile[cc * 16 + k][dr]);
  __hip_bfloat16* dst = Wt + ((size_t)e * D_SZ + d0 + dr) * F_SZ + f0 + cc * 16;
  ((bhalf8*)dst)[0] = pk.v[0];
  ((bhalf8*)dst)[1] = pk.v[1];
}

// ---------------- async 16B global -> LDS ----------------
__device__ __forceinline__ void load_lds16(const __hip_bfloat16* g, __hip_bfloat16* l) {
  __builtin_amdgcn_global_load_lds((const __attribute__((address_space(1))) void*)g,
                                   (__attribute__((address_space(3))) void*)l, 16, 0, 0);
}

// ---------------- gather GEMM: BM=64, BN=128, BK=64, pipelined ----------------
// 8 waves (2m x 4n), wave tile 32x32, 8 MFMA/iter/wave.
// XCD-chunked block swizzle: each XCD gets 66 consecutive logical blocks
// (33 m-tiles, both n-siblings) -> A's 2nd read is an L2 hit, Wt working set
// per XCD ~1-2 MB -> B stages from L2.
// Double-buffered As/Bs; B-DMA prefetch distance 1; A-reg prefetch distance 2
// (two static register sets via unroll-by-2). End-of-iter s_waitcnt vmcnt(2)
// drains [A(k+2), B(k+1)] and leaves A(k+3) in flight across the barrier.
// LDS layouts (bf16, row stride 64 elems = 128B) XOR-swizzled: 16B chunk c at
// physical (c ^ (row&7)) -> fragment ds_read_b128 is 2-way aliased (free).
__launch_bounds__(512, 4)
__global__ void k_gemm(const float* __restrict__ x, const __hip_bfloat16* __restrict__ Wt,
                       const float* __restrict__ bias, const int* __restrict__ counts,
                       const int* __restrict__ perm, float* __restrict__ out) {
  // XCD-aware remap (GRID_G % 8 == 0 -> bijective)
  int bid = blockIdx.x;
  int id = (bid & 7) * XCHUNK + (bid >> 3);
  int nb = (id & 1) * 128;
  int mt = id >> 1;
  int e = -1, mbase = 0, count = 0;
  {
    int acc0 = 0;
#pragma unroll
    for (int ee = 0; ee < E_SZ; ++ee) {
      int c = counts[ee];
      int nt = (c + 63) >> 6;
      if (e < 0 && mt < acc0 + nt) { e = ee; mbase = (mt - acc0) * 64; count = c; }
      acc0 += nt;
    }
  }
  if (e < 0) return;

  __shared__ __align__(16) __hip_bfloat16 As[2 * 64 * 64];    // 16 KB (2 bufs)
  __shared__ __align__(16) __hip_bfloat16 Bs[2 * 128 * 64];   // 32 KB (2 bufs)

  int t = threadIdx.x;
  int w = t >> 6;
  int lane = t & 63;
  int wm = w >> 2, wn = w & 3;
  int l15 = lane & 15;
  int q = lane >> 4;

  const int* permE = perm + e * B_SZ;

  // ---- A staging setup: float4 index fi = i*512+t -> row i*32+(t>>4), k=(t&15)*4 ----
  int tr = t >> 4;      // 0..31
  int tc = t & 15;      // float4 index within row
  const float* pA[2];
  int wAo[2];           // As element offset for this thread's ds_write (8B each)
#pragma unroll
  for (int i = 0; i < 2; ++i) {
    int r = i * 32 + tr;
    int gm = mbase + r;
    int src = permE[(gm < count) ? gm : mbase];
    pA[i] = x + (size_t)src * F_SZ + tc * 4;
    int cw = tc >> 1, half = tc & 1;
    wAo[i] = r * 64 + ((cw ^ (r & 7)) * 8) + half * 4;
  }

  // ---- B staging setup: physical chunk p = i*512+t; n=p>>3; logical chunk=(p&7)^(n&7) ----
  const __hip_bfloat16* pB[2];
  int dB[2];            // wave-uniform LDS elem offset (HW adds lane*16B)
#pragma unroll
  for (int i = 0; i < 2; ++i) {
    int p = i * 512 + t;
    int n = p >> 3;
    int cl = (p & 7) ^ (n & 7);
    pB[i] = Wt + (size_t)(e * D_SZ + nb + n) * F_SZ + cl * 8;
    dB[i] = i * 4096 + w * 512;
  }

  // fragment read offsets (element units)
  int rAo[2][2], rBo[2][2];
#pragma unroll
  for (int ks = 0; ks < 2; ++ks) {
#pragma unroll
    for (int i = 0; i < 2; ++i) {
      int m = wm * 32 + i * 16 + l15;
      rAo[ks][i] = m * 64 + (((ks * 4 + q) ^ (m & 7)) * 8);
    }
#pragma unroll
    for (int j = 0; j < 2; ++j) {
      int n = wn * 32 + j * 16 + l15;
      rBo[ks][j] = n * 64 + (((ks * 4 + q) ^ (n & 7)) * 8);
    }
  }

  fl4 zz = {0.0f, 0.0f, 0.0f, 0.0f};
  fl4 acc[2][2];
#pragma unroll
  for (int i = 0; i < 2; ++i)
#pragma unroll
    for (int j = 0; j < 2; ++j) acc[i][j] = zz;

  float4 avA[2], avB[2];

  // ---------------- prologue ----------------
  // B(0) -> Bs0
#pragma unroll
  for (int i = 0; i < 2; ++i) load_lds16(pB[i], Bs + dB[i]);
  __builtin_amdgcn_sched_barrier(0);
  // A(0) -> regs -> cvt -> As0 (compiler-inserted wait drains B(0) too; prologue-only cost)
  {
    float4 avP[2];
#pragma unroll
    for (int i = 0; i < 2; ++i) avP[i] = *(const float4*)(pA[i]);
#pragma unroll
    for (int i = 0; i < 2; ++i) {
      short4 s;
      s.x = f2b(avP[i].x); s.y = f2b(avP[i].y);
      s.z = f2b(avP[i].z); s.w = f2b(avP[i].w);
      *(short4*)(As + wAo[i]) = s;
    }
  }
  // A(1), A(2) in flight
#pragma unroll
  for (int i = 0; i < 2; ++i) avA[i] = *(const float4*)(pA[i] + 64);
#pragma unroll
  for (int i = 0; i < 2; ++i) avB[i] = *(const float4*)(pA[i] + 128);
  __builtin_amdgcn_sched_barrier(0);
  asm volatile("s_waitcnt vmcnt(4) lgkmcnt(0)");
  __builtin_amdgcn_sched_barrier(0);
  __builtin_amdgcn_s_barrier();
  __builtin_amdgcn_sched_barrier(0);

  // ---- one pipelined iteration: compute tile k, cvt tile k+1 (from AV), load tile k+3 ----
#define ITER(kk, AV)                                                                  \
  do {                                                                                \
    int cb_ = (kk) & 1, nx_ = cb_ ^ 1;                                                \
    _Pragma("unroll")                                                                 \
    for (int i = 0; i < 2; ++i)                                                       \
      load_lds16(pB[i] + ((kk) + 1) * 64, Bs + nx_ * 8192 + dB[i]);                   \
    __builtin_amdgcn_sched_barrier(0);                                                \
    _Pragma("unroll")                                                                 \
    for (int i = 0; i < 2; ++i) {                                                     \
      short4 s;                                                                       \
      s.x = f2b(AV[i].x); s.y = f2b(AV[i].y);                                         \
      s.z = f2b(AV[i].z); s.w = f2b(AV[i].w);                                         \
      *(short4*)(As + nx_ * 4096 + wAo[i]) = s;                                       \
    }                                                                                 \
    {                                                                                 \
      int kn_ = ((kk) + 3) & 31;                                                      \
      _Pragma("unroll")                                                               \
      for (int i = 0; i < 2; ++i) AV[i] = *(const float4*)(pA[i] + kn_ * 64);         \
    }                                                                                 \
    {                                                                                 \
      const __hip_bfloat16* Ab_ = As + cb_ * 4096;                                    \
      const __hip_bfloat16* Bb_ = Bs + cb_ * 8192;                                    \
      _Pragma("unroll")                                                               \
      for (int ks = 0; ks < 2; ++ks) {                                                \
        bhalf8 af[2], bf[2];                                                          \
        _Pragma("unroll")                                                             \
        for (int i = 0; i < 2; ++i) af[i] = *(const bhalf8*)(Ab_ + rAo[ks][i]);       \
        _Pragma("unroll")                                                             \
        for (int j = 0; j < 2; ++j) bf[j] = *(const bhalf8*)(Bb_ + rBo[ks][j]);       \
        _Pragma("unroll")                                                             \
        for (int i = 0; i < 2; ++i)                                                   \
          _Pragma("unroll")                                                           \
          for (int j = 0; j < 2; ++j)                                                 \
            acc[i][j] = __builtin_amdgcn_mfma_f32_16x16x32_bf16(af[i], bf[j],         \
                                                                acc[i][j], 0, 0, 0); \
      }                                                                               \
    }                                                                                 \
    __builtin_amdgcn_sched_barrier(0);                                                \
    asm volatile("s_waitcnt vmcnt(2) lgkmcnt(0)");                                    \
    __builtin_amdgcn_sched_barrier(0);                                                \
    __builtin_amdgcn_s_barrier();                                                     \
    __builtin_amdgcn_sched_barrier(0);                                                \
  } while (0)

  // ---------------- main loop: tiles 0..30 computed here, 31 in tail ----------------
  for (int k = 0; k < 30; k += 2) {
    ITER(k, avA);
    ITER(k + 1, avB);
  }
  ITER(30, avA);
#undef ITER

  // keep the tail prefetches alive so the vmcnt discipline is not broken by DCE
  asm volatile("" :: "v"(avA[0].x), "v"(avA[1].x), "v"(avB[0].x), "v"(avB[1].x));

  // tail: compute tile 31 from buffer 1
  {
    const __hip_bfloat16* Ab = As + 4096;
    const __hip_bfloat16* Bb = Bs + 8192;
#pragma unroll
    for (int ks = 0; ks < 2; ++ks) {
      bhalf8 af[2], bf[2];
#pragma unroll
      for (int i = 0; i < 2; ++i) af[i] = *(const bhalf8*)(Ab + rAo[ks][i]);
#pragma unroll
      for (int j = 0; j < 2; ++j) bf[j] = *(const bhalf8*)(Bb + rBo[ks][j]);
#pragma unroll
      for (int i = 0; i < 2; ++i)
#pragma unroll
        for (int j = 0; j < 2; ++j)
          acc[i][j] = __builtin_amdgcn_mfma_f32_16x16x32_bf16(af[i], bf[j], acc[i][j], 0, 0, 0);
    }
  }

  // epilogue: C/D layout col = lane&15, row = q*4 + reg
  float bv[2];
#pragma unroll
  for (int j = 0; j < 2; ++j) bv[j] = bias[e * D_SZ + nb + wn * 32 + j * 16 + l15];

#pragma unroll
  for (int i = 0; i < 2; ++i) {
#pragma unroll
    for (int r = 0; r < 4; ++r) {
      int gm = mbase + wm * 32 + i * 16 + q * 4 + r;
      if (gm < count) {
        int row = permE[gm];
        float* po = out + (size_t)row * D_SZ + nb + wn * 32;
#pragma unroll
        for (int j = 0; j < 2; ++j) po[j * 16 + l15] = acc[i][j][r] + bv[j];
      }
    }
  }
}

extern "C" void kernel_launch(void* const* d_in, const int* in_sizes, int n_in,
                              void* d_out, int out_size, void* d_ws, size_t ws_size,
                              hipStream_t stream) {
  const float* x = (const float*)d_in[0];
  const float* W = (const float*)d_in[1];
  const float* bias = (const float*)d_in[2];
  const int* ids = (const int*)d_in[3];
  float* out = (float*)d_out;

  char* ws = (char*)d_ws;
  int* counts = (int*)ws;                                 // 32 B
  int* perm = (int*)(ws + 256);                           // 512 KB
  __hip_bfloat16* Wt = (__hip_bfloat16*)(ws + (1 << 20)); // 8 MB

  hipMemsetAsync(counts, 0, E_SZ * sizeof(int), stream);
  k_scatter<<<B_SZ / 256, 256, 0, stream>>>(ids, counts, perm);
  k_transpose<<<dim3(F_SZ / 64, D_SZ / 64, E_SZ), 256, 0, stream>>>(W, Wt);
  k_gemm<<<GRID_G, 512, 0, stream>>>(x, Wt, bias, counts, perm, out);
}

// Round 4
// 254.598 us; speedup vs baseline: 1.0041x; 1.0041x over previous
//
#include <hip/hip_runtime.h>
#include <hip/hip_bf16.h>

#define B_SZ 16384
#define F_SZ 2048
#define D_SZ 256
#define E_SZ 8
#define GRID_G 264   // sum_e ceil(count_e/64) <= 263; one n-tile (BN=256=D); 264 % 8 == 0
#define XCHUNK (GRID_G / 8)

typedef __attribute__((ext_vector_type(8))) short bhalf8;
typedef __attribute__((ext_vector_type(4))) float fl4;

__device__ __forceinline__ short f2b(float f) {
  __hip_bfloat16 h = __float2bfloat16(f);
  union { __hip_bfloat16 h; short s; } u;
  u.h = h;
  return u.s;
}

// ---------------- bucket scatter ----------------
__global__ void k_scatter(const int* __restrict__ ids, int* __restrict__ counts,
                          int* __restrict__ perm) {
  __shared__ int lcnt[E_SZ], lbase[E_SZ];
  int t = threadIdx.x;
  if (t < E_SZ) lcnt[t] = 0;
  __syncthreads();
  int b = blockIdx.x * 256 + t;
  int e = ids[b];
  int p = atomicAdd(&lcnt[e], 1);
  __syncthreads();
  if (t < E_SZ) lbase[t] = atomicAdd(&counts[t], lcnt[t]);
  __syncthreads();
  perm[e * B_SZ + lbase[e] + p] = b;
}

// ---------------- W transpose+cast: Wt[e][d][f] = bf16(W[e][f][d]) ----------------
__global__ void k_transpose(const float* __restrict__ W, __hip_bfloat16* __restrict__ Wt) {
  __shared__ float tile[64][65];
  int e = blockIdx.z;
  int f0 = blockIdx.x * 64;
  int d0 = blockIdx.y * 64;
  int t = threadIdx.x;
  const float* src = W + ((size_t)e * F_SZ + f0) * D_SZ + d0;
  int fr = t >> 2, c0 = t & 3;
#pragma unroll
  for (int c = c0; c < 16; c += 4) {
    float4 v = *(const float4*)(src + (size_t)fr * D_SZ + c * 4);
    tile[fr][c * 4 + 0] = v.x;
    tile[fr][c * 4 + 1] = v.y;
    tile[fr][c * 4 + 2] = v.z;
    tile[fr][c * 4 + 3] = v.w;
  }
  __syncthreads();
  int dr = t >> 2, cc = t & 3;
  union { unsigned short u[16]; bhalf8 v[2]; } pk;
#pragma unroll
  for (int k = 0; k < 16; ++k) pk.u[k] = (unsigned short)f2b(tile[cc * 16 + k][dr]);
  __hip_bfloat16* dst = Wt + ((size_t)e * D_SZ + d0 + dr) * F_SZ + f0 + cc * 16;
  ((bhalf8*)dst)[0] = pk.v[0];
  ((bhalf8*)dst)[1] = pk.v[1];
}

// ---------------- async 16B global -> LDS ----------------
__device__ __forceinline__ void load_lds16(const __hip_bfloat16* g, __hip_bfloat16* l) {
  __builtin_amdgcn_global_load_lds((const __attribute__((address_space(1))) void*)g,
                                   (__attribute__((address_space(3))) void*)l, 16, 0, 0);
}

// ---------------- gather GEMM: BM=64, BN=256 (full D), BK=64, pipelined ----------------
// [resubmission of R3 — R3 bench died in the harness (Trio nursery) with no
//  kernel-side failure evidence; vmcnt ledger & buffer parity re-audited OK]
// 8 waves (2m x 4n), wave tile 32x64, 16 MFMA/iter/wave.
// BN=256 removes the n-sibling: each x row gathered ONCE -> CU-side traffic
// 537 -> 403 MB (time has tracked CU-side bytes at ~5.6 TB/s across 3 rounds).
// Grid 264 ~= 1 block/CU (<=8 CUs get a 2nd co-resident block; LDS 80KB -> 2/CU ok).
// Pipeline: Bs double-buffered (4 DMA/thread/iter), A-reg prefetch distance 2
// (avA/avB sets, loads tile k+3 during iter k). End-of-iter s_waitcnt vmcnt(2)
// drains [A(k+2)x2, B(k+1)x4], keeps A(k+3)x2 in flight across the barrier.
// LDS rows 64 elems (128B), 16B chunk c stored at (c ^ (row&7)) -> ds_read_b128
// fragment reads are 2-way aliased (free).
__launch_bounds__(512, 4)
__global__ void k_gemm(const float* __restrict__ x, const __hip_bfloat16* __restrict__ Wt,
                       const float* __restrict__ bias, const int* __restrict__ counts,
                       const int* __restrict__ perm, float* __restrict__ out) {
  // XCD-aware remap (GRID_G % 8 == 0 -> bijective); one expert's Wt slice per XCD
  int bid = blockIdx.x;
  int mt = (bid & 7) * XCHUNK + (bid >> 3);
  int e = -1, mbase = 0, count = 0;
  {
    int acc0 = 0;
#pragma unroll
    for (int ee = 0; ee < E_SZ; ++ee) {
      int c = counts[ee];
      int nt = (c + 63) >> 6;
      if (e < 0 && mt < acc0 + nt) { e = ee; mbase = (mt - acc0) * 64; count = c; }
      acc0 += nt;
    }
  }
  if (e < 0) return;

  __shared__ __align__(16) __hip_bfloat16 As[2 * 64 * 64];     // 16 KB (2 bufs)
  __shared__ __align__(16) __hip_bfloat16 Bs[2 * 256 * 64];    // 64 KB (2 bufs)

  int t = threadIdx.x;
  int w = t >> 6;
  int lane = t & 63;
  int wm = w >> 2, wn = w & 3;
  int l15 = lane & 15;
  int q = lane >> 4;

  const int* permE = perm + e * B_SZ;

  // ---- A staging: float4 index = i*512+t -> row i*32+(t>>4), k-chunk (t&15) ----
  int tr = t >> 4;      // 0..31
  int tc = t & 15;      // float4 index within row
  const float* pA[2];
  int wAo[2];           // As element offset for this thread's ds_write (8B each)
#pragma unroll
  for (int i = 0; i < 2; ++i) {
    int r = i * 32 + tr;
    int gm = mbase + r;
    int src = permE[(gm < count) ? gm : mbase];
    pA[i] = x + (size_t)src * F_SZ + tc * 4;
    int cw = tc >> 1, half = tc & 1;
    wAo[i] = r * 64 + ((cw ^ (r & 7)) * 8) + half * 4;
  }

  // ---- B staging: physical 16B chunk p = i*512+t; n=p>>3; logical chunk=(p&7)^(n&7) ----
  const __hip_bfloat16* pB[4];
  int dB[4];            // wave-uniform LDS elem offset within a buffer (HW adds lane*16B)
#pragma unroll
  for (int i = 0; i < 4; ++i) {
    int p = i * 512 + t;
    int n = p >> 3;                  // 0..255
    int cl = (p & 7) ^ (n & 7);
    pB[i] = Wt + (size_t)(e * D_SZ + n) * F_SZ + cl * 8;
    dB[i] = i * 4096 + w * 512;
  }

  // fragment read offsets (element units)
  int rAo[2][2], rBo[2][4];
#pragma unroll
  for (int ks = 0; ks < 2; ++ks) {
#pragma unroll
    for (int i = 0; i < 2; ++i) {
      int m = wm * 32 + i * 16 + l15;
      rAo[ks][i] = m * 64 + (((ks * 4 + q) ^ (m & 7)) * 8);
    }
#pragma unroll
    for (int j = 0; j < 4; ++j) {
      int n = wn * 64 + j * 16 + l15;
      rBo[ks][j] = n * 64 + (((ks * 4 + q) ^ (n & 7)) * 8);
    }
  }

  fl4 zz = {0.0f, 0.0f, 0.0f, 0.0f};
  fl4 acc[2][4];
#pragma unroll
  for (int i = 0; i < 2; ++i)
#pragma unroll
    for (int j = 0; j < 4; ++j) acc[i][j] = zz;

  float4 avA[2], avB[2];

  // ---------------- prologue ----------------
  // B(0) -> Bs0
#pragma unroll
  for (int i = 0; i < 4; ++i) load_lds16(pB[i], Bs + dB[i]);
  __builtin_amdgcn_sched_barrier(0);
  // A(0) -> regs -> cvt -> As0 (auto-wait drains B(0) too; prologue-only cost)
  {
    float4 avP[2];
#pragma unroll
    for (int i = 0; i < 2; ++i) avP[i] = *(const float4*)(pA[i]);
#pragma unroll
    for (int i = 0; i < 2; ++i) {
      short4 s;
      s.x = f2b(avP[i].x); s.y = f2b(avP[i].y);
      s.z = f2b(avP[i].z); s.w = f2b(avP[i].w);
      *(short4*)(As + wAo[i]) = s;
    }
  }
  // A(1), A(2) in flight
#pragma unroll
  for (int i = 0; i < 2; ++i) avA[i] = *(const float4*)(pA[i] + 64);
#pragma unroll
  for (int i = 0; i < 2; ++i) avB[i] = *(const float4*)(pA[i] + 128);
  __builtin_amdgcn_sched_barrier(0);
  asm volatile("s_waitcnt vmcnt(4) lgkmcnt(0)");
  __builtin_amdgcn_sched_barrier(0);
  __builtin_amdgcn_s_barrier();
  __builtin_amdgcn_sched_barrier(0);

  // ---- one pipelined iteration: compute tile kk, cvt tile kk+1 (AV), load tile kk+3 ----
#define ITER(kk, AV)                                                                  \
  do {                                                                                \
    int cb_ = (kk) & 1, nx_ = cb_ ^ 1;                                                \
    _Pragma("unroll")                                                                 \
    for (int i = 0; i < 4; ++i)                                                       \
      load_lds16(pB[i] + ((kk) + 1) * 64, Bs + nx_ * 16384 + dB[i]);                  \
    __builtin_amdgcn_sched_barrier(0);                                                \
    _Pragma("unroll")                                                                 \
    for (int i = 0; i < 2; ++i) {                                                     \
      short4 s;                                                                       \
      s.x = f2b(AV[i].x); s.y = f2b(AV[i].y);                                         \
      s.z = f2b(AV[i].z); s.w = f2b(AV[i].w);                                         \
      *(short4*)(As + nx_ * 4096 + wAo[i]) = s;                                       \
    }                                                                                 \
    {                                                                                 \
      int kn_ = ((kk) + 3) & 31;                                                      \
      _Pragma("unroll")                                                               \
      for (int i = 0; i < 2; ++i) AV[i] = *(const float4*)(pA[i] + kn_ * 64);         \
    }                                                                                 \
    {                                                                                 \
      const __hip_bfloat16* Ab_ = As + cb_ * 4096;                                    \
      const __hip_bfloat16* Bb_ = Bs + cb_ * 16384;                                   \
      _Pragma("unroll")                                                               \
      for (int ks = 0; ks < 2; ++ks) {                                                \
        bhalf8 af[2], bf[4];                                                          \
        _Pragma("unroll")                                                             \
        for (int i = 0; i < 2; ++i) af[i] = *(const bhalf8*)(Ab_ + rAo[ks][i]);       \
        _Pragma("unroll")                                                             \
        for (int j = 0; j < 4; ++j) bf[j] = *(const bhalf8*)(Bb_ + rBo[ks][j]);       \
        _Pragma("unroll")                                                             \
        for (int i = 0; i < 2; ++i)                                                   \
          _Pragma("unroll")                                                           \
          for (int j = 0; j < 4; ++j)                                                 \
            acc[i][j] = __builtin_amdgcn_mfma_f32_16x16x32_bf16(af[i], bf[j],         \
                                                                acc[i][j], 0, 0, 0); \
      }                                                                               \
    }                                                                                 \
    __builtin_amdgcn_sched_barrier(0);                                                \
    asm volatile("s_waitcnt vmcnt(2) lgkmcnt(0)");                                    \
    __builtin_amdgcn_sched_barrier(0);                                                \
    __builtin_amdgcn_s_barrier();                                                     \
    __builtin_amdgcn_sched_barrier(0);                                                \
  } while (0)

  // ---------------- main loop: tiles 0..30 computed here, 31 in tail ----------------
  for (int k = 0; k < 30; k += 2) {
    ITER(k, avA);
    ITER(k + 1, avB);
  }
  ITER(30, avA);
#undef ITER

  // keep the tail prefetches alive so the vmcnt discipline is not broken by DCE
  asm volatile("" :: "v"(avA[0].x), "v"(avA[1].x), "v"(avB[0].x), "v"(avB[1].x));

  // tail: compute tile 31 from buffer 1
  {
    const __hip_bfloat16* Ab = As + 4096;
    const __hip_bfloat16* Bb = Bs + 16384;
#pragma unroll
    for (int ks = 0; ks < 2; ++ks) {
      bhalf8 af[2], bf[4];
#pragma unroll
      for (int i = 0; i < 2; ++i) af[i] = *(const bhalf8*)(Ab + rAo[ks][i]);
#pragma unroll
      for (int j = 0; j < 4; ++j) bf[j] = *(const bhalf8*)(Bb + rBo[ks][j]);
#pragma unroll
      for (int i = 0; i < 2; ++i)
#pragma unroll
        for (int j = 0; j < 4; ++j)
          acc[i][j] = __builtin_amdgcn_mfma_f32_16x16x32_bf16(af[i], bf[j], acc[i][j], 0, 0, 0);
    }
  }

  // epilogue: C/D layout col = lane&15, row = q*4 + reg
  float bv[4];
#pragma unroll
  for (int j = 0; j < 4; ++j) bv[j] = bias[e * D_SZ + wn * 64 + j * 16 + l15];

#pragma unroll
  for (int i = 0; i < 2; ++i) {
#pragma unroll
    for (int r = 0; r < 4; ++r) {
      int gm = mbase + wm * 32 + i * 16 + q * 4 + r;
      if (gm < count) {
        int row = permE[gm];
        float* po = out + (size_t)row * D_SZ + wn * 64;
#pragma unroll
        for (int j = 0; j < 4; ++j) po[j * 16 + l15] = acc[i][j][r] + bv[j];
      }
    }
  }
}

extern "C" void kernel_launch(void* const* d_in, const int* in_sizes, int n_in,
                              void* d_out, int out_size, void* d_ws, size_t ws_size,
                              hipStream_t stream) {
  const float* x = (const float*)d_in[0];
  const float* W = (const float*)d_in[1];
  const float* bias = (const float*)d_in[2];
  const int* ids = (const int*)d_in[3];
  float* out = (float*)d_out;

  char* ws = (char*)d_ws;
  int* counts = (int*)ws;                                 // 32 B
  int* perm = (int*)(ws + 256);                           // 512 KB
  __hip_bfloat16* Wt = (__hip_bfloat16*)(ws + (1 << 20)); // 8 MB

  hipMemsetAsync(counts, 0, E_SZ * sizeof(int), stream);
  k_scatter<<<B_SZ / 256, 256, 0, stream>>>(ids, counts, perm);
  k_transpose<<<dim3(F_SZ / 64, D_SZ / 64, E_SZ), 256, 0, stream>>>(W, Wt);
  k_gemm<<<GRID_G, 512, 0, stream>>>(x, Wt, bias, counts, perm, out);
}

// Round 5
// 236.291 us; speedup vs baseline: 1.0819x; 1.0775x over previous
//
#include <hip/hip_runtime.h>
#include <hip/hip_bf16.h>

#define B_SZ 16384
#define F_SZ 2048
#define D_SZ 256
#define E_SZ 8
#define GRID_G 184   // >= max tiles (sum_e ceil(count_e/96) <= 178); 184 = 8*23
#define XCHUNK (GRID_G / 8)

typedef __attribute__((ext_vector_type(8))) short bhalf8;
typedef __attribute__((ext_vector_type(4))) float fl4;

__device__ __forceinline__ short f2b(float f) {
  __hip_bfloat16 h = __float2bfloat16(f);
  union { __hip_bfloat16 h; short s; } u;
  u.h = h;
  return u.s;
}

// ---------------- bucket scatter ----------------
__global__ void k_scatter(const int* __restrict__ ids, int* __restrict__ counts,
                          int* __restrict__ perm) {
  __shared__ int lcnt[E_SZ], lbase[E_SZ];
  int t = threadIdx.x;
  if (t < E_SZ) lcnt[t] = 0;
  __syncthreads();
  int b = blockIdx.x * 256 + t;
  int e = ids[b];
  int p = atomicAdd(&lcnt[e], 1);
  __syncthreads();
  if (t < E_SZ) lbase[t] = atomicAdd(&counts[t], lcnt[t]);
  __syncthreads();
  perm[e * B_SZ + lbase[e] + p] = b;
}

// ---------------- W transpose+cast: Wt[e][d][f] = bf16(W[e][f][d]) ----------------
__global__ void k_transpose(const float* __restrict__ W, __hip_bfloat16* __restrict__ Wt) {
  __shared__ float tile[64][65];
  int e = blockIdx.z;
  int f0 = blockIdx.x * 64;
  int d0 = blockIdx.y * 64;
  int t = threadIdx.x;
  const float* src = W + ((size_t)e * F_SZ + f0) * D_SZ + d0;
  int fr = t >> 2, c0 = t & 3;
#pragma unroll
  for (int c = c0; c < 16; c += 4) {
    float4 v = *(const float4*)(src + (size_t)fr * D_SZ + c * 4);
    tile[fr][c * 4 + 0] = v.x;
    tile[fr][c * 4 + 1] = v.y;
    tile[fr][c * 4 + 2] = v.z;
    tile[fr][c * 4 + 3] = v.w;
  }
  __syncthreads();
  int dr = t >> 2, cc = t & 3;
  union { unsigned short u[16]; bhalf8 v[2]; } pk;
#pragma unroll
  for (int k = 0; k < 16; ++k) pk.u[k] = (unsigned short)f2b(tile[cc * 16 + k][dr]);
  __hip_bfloat16* dst = Wt + ((size_t)e * D_SZ + d0 + dr) * F_SZ + f0 + cc * 16;
  ((bhalf8*)dst)[0] = pk.v[0];
  ((bhalf8*)dst)[1] = pk.v[1];
}

// ---------------- async 16B global -> LDS ----------------
__device__ __forceinline__ void load_lds16(const __hip_bfloat16* g, __hip_bfloat16* l) {
  __builtin_amdgcn_global_load_lds((const __attribute__((address_space(1))) void*)g,
                                   (__attribute__((address_space(3))) void*)l, 16, 0, 0);
}

// ---------------- gather GEMM: BM=96, BN=256 (full D), BK=64, pipelined ----------------
// R4 lesson: grid 264 on 256 CUs with 1-block residency => 8 straggler CUs run
// 2 tiles SERIALLY (93us = 2 x 46.5us single-tile) while 248 CUs idle.
// BM=96 caps tiles at sum_e ceil(count_e/96) <= 178 < 256 -> every block gets
// its own CU, zero stragglers, no atomics. Per-CU bytes 1.84 MB (was 3.2 max).
// 8 waves (2m x 4n), wave tile 48x64: acc[3][4], 24 MFMA/wave/iter.
// Pipeline: Bs double-buffered (4 DMA/thread/iter); A-reg prefetch distance 2
// (avA/avB sets of 3 float4, loads tile k+3 during iter k). End-of-iter
// s_waitcnt vmcnt(3) drains [A(k+2)x3, B(k+1)x4], keeps A(k+3)x3 in flight.
// LDS: As 2x96x64x2B = 24KB, Bs 2x256x64x2B = 64KB -> 88KB (1 block/CU, fine
// since blocks < CUs). LDS rows 64 elems (128B), 16B chunk c at (c ^ (row&7))
// -> ds_read_b128 fragment reads 2-way aliased (free).
__launch_bounds__(512, 2)
__global__ void k_gemm(const float* __restrict__ x, const __hip_bfloat16* __restrict__ Wt,
                       const float* __restrict__ bias, const int* __restrict__ counts,
                       const int* __restrict__ perm, float* __restrict__ out) {
  // XCD-aware remap (184 = 8*23, bijective); one expert's Wt slice per 1-2 XCDs
  int bid = blockIdx.x;
  int mt = (bid & 7) * XCHUNK + (bid >> 3);
  int e = -1, mbase = 0, count = 0;
  {
    int acc0 = 0;
#pragma unroll
    for (int ee = 0; ee < E_SZ; ++ee) {
      int c = counts[ee];
      int nt = (c + 95) / 96;
      if (e < 0 && mt < acc0 + nt) { e = ee; mbase = (mt - acc0) * 96; count = c; }
      acc0 += nt;
    }
  }
  if (e < 0) return;

  __shared__ __align__(16) __hip_bfloat16 As[2 * 96 * 64];     // 24 KB (2 bufs)
  __shared__ __align__(16) __hip_bfloat16 Bs[2 * 256 * 64];    // 64 KB (2 bufs)

  int t = threadIdx.x;
  int w = t >> 6;
  int lane = t & 63;
  int wm = w >> 2, wn = w & 3;
  int l15 = lane & 15;
  int q = lane >> 4;

  const int* permE = perm + e * B_SZ;

  // ---- A staging: float4 index = i*512+t -> row i*32+(t>>4), k-chunk (t&15) ----
  int tr = t >> 4;      // 0..31
  int tc = t & 15;      // float4 index within row
  const float* pA[3];
  int wAo[3];           // As element offset for this thread's ds_write (8B each)
#pragma unroll
  for (int i = 0; i < 3; ++i) {
    int r = i * 32 + tr;                 // 0..95
    int gm = mbase + r;
    int src = permE[(gm < count) ? gm : mbase];
    pA[i] = x + (size_t)src * F_SZ + tc * 4;
    int cw = tc >> 1, half = tc & 1;
    wAo[i] = r * 64 + ((cw ^ (r & 7)) * 8) + half * 4;
  }

  // ---- B staging: physical 16B chunk p = i*512+t; n=p>>3; logical chunk=(p&7)^(n&7) ----
  const __hip_bfloat16* pB[4];
  int dB[4];            // wave-uniform LDS elem offset within a buffer (HW adds lane*16B)
#pragma unroll
  for (int i = 0; i < 4; ++i) {
    int p = i * 512 + t;
    int n = p >> 3;                  // 0..255
    int cl = (p & 7) ^ (n & 7);
    pB[i] = Wt + (size_t)(e * D_SZ + n) * F_SZ + cl * 8;
    dB[i] = i * 4096 + w * 512;
  }

  // fragment read offsets (element units)
  int rAo[2][3], rBo[2][4];
#pragma unroll
  for (int ks = 0; ks < 2; ++ks) {
#pragma unroll
    for (int i = 0; i < 3; ++i) {
      int m = wm * 48 + i * 16 + l15;    // 0..95
      rAo[ks][i] = m * 64 + (((ks * 4 + q) ^ (m & 7)) * 8);
    }
#pragma unroll
    for (int j = 0; j < 4; ++j) {
      int n = wn * 64 + j * 16 + l15;
      rBo[ks][j] = n * 64 + (((ks * 4 + q) ^ (n & 7)) * 8);
    }
  }

  fl4 zz = {0.0f, 0.0f, 0.0f, 0.0f};
  fl4 acc[3][4];
#pragma unroll
  for (int i = 0; i < 3; ++i)
#pragma unroll
    for (int j = 0; j < 4; ++j) acc[i][j] = zz;

  float4 avA[3], avB[3];

  // ---------------- prologue ----------------
  // B(0) -> Bs0
#pragma unroll
  for (int i = 0; i < 4; ++i) load_lds16(pB[i], Bs + dB[i]);
  __builtin_amdgcn_sched_barrier(0);
  // A(0) -> regs -> cvt -> As0 (auto-wait drains B(0) too; prologue-only cost)
  {
    float4 avP[3];
#pragma unroll
    for (int i = 0; i < 3; ++i) avP[i] = *(const float4*)(pA[i]);
#pragma unroll
    for (int i = 0; i < 3; ++i) {
      short4 s;
      s.x = f2b(avP[i].x); s.y = f2b(avP[i].y);
      s.z = f2b(avP[i].z); s.w = f2b(avP[i].w);
      *(short4*)(As + wAo[i]) = s;
    }
  }
  // A(1), A(2) in flight
#pragma unroll
  for (int i = 0; i < 3; ++i) avA[i] = *(const float4*)(pA[i] + 64);
#pragma unroll
  for (int i = 0; i < 3; ++i) avB[i] = *(const float4*)(pA[i] + 128);
  __builtin_amdgcn_sched_barrier(0);
  asm volatile("s_waitcnt vmcnt(6) lgkmcnt(0)");
  __builtin_amdgcn_sched_barrier(0);
  __builtin_amdgcn_s_barrier();
  __builtin_amdgcn_sched_barrier(0);

  // ---- one pipelined iteration: compute tile kk, cvt tile kk+1 (AV), load tile kk+3 ----
#define ITER(kk, AV)                                                                  \
  do {                                                                                \
    int cb_ = (kk) & 1, nx_ = cb_ ^ 1;                                                \
    _Pragma("unroll")                                                                 \
    for (int i = 0; i < 4; ++i)                                                       \
      load_lds16(pB[i] + ((kk) + 1) * 64, Bs + nx_ * 16384 + dB[i]);                  \
    __builtin_amdgcn_sched_barrier(0);                                                \
    _Pragma("unroll")                                                                 \
    for (int i = 0; i < 3; ++i) {                                                     \
      short4 s;                                                                       \
      s.x = f2b(AV[i].x); s.y = f2b(AV[i].y);                                         \
      s.z = f2b(AV[i].z); s.w = f2b(AV[i].w);                                         \
      *(short4*)(As + nx_ * 6144 + wAo[i]) = s;                                       \
    }                                                                                 \
    {                                                                                 \
      int kn_ = ((kk) + 3) & 31;                                                      \
      _Pragma("unroll")                                                               \
      for (int i = 0; i < 3; ++i) AV[i] = *(const float4*)(pA[i] + kn_ * 64);         \
    }                                                                                 \
    {                                                                                 \
      const __hip_bfloat16* Ab_ = As + cb_ * 6144;                                    \
      const __hip_bfloat16* Bb_ = Bs + cb_ * 16384;                                   \
      _Pragma("unroll")                                                               \
      for (int ks = 0; ks < 2; ++ks) {                                                \
        bhalf8 af[3], bf[4];                                                          \
        _Pragma("unroll")                                                             \
        for (int i = 0; i < 3; ++i) af[i] = *(const bhalf8*)(Ab_ + rAo[ks][i]);       \
        _Pragma("unroll")                                                             \
        for (int j = 0; j < 4; ++j) bf[j] = *(const bhalf8*)(Bb_ + rBo[ks][j]);       \
        _Pragma("unroll")                                                             \
        for (int i = 0; i < 3; ++i)                                                   \
          _Pragma("unroll")                                                           \
          for (int j = 0; j < 4; ++j)                                                 \
            acc[i][j] = __builtin_amdgcn_mfma_f32_16x16x32_bf16(af[i], bf[j],         \
                                                                acc[i][j], 0, 0, 0); \
      }                                                                               \
    }                                                                                 \
    __builtin_amdgcn_sched_barrier(0);                                                \
    asm volatile("s_waitcnt vmcnt(3) lgkmcnt(0)");                                    \
    __builtin_amdgcn_sched_barrier(0);                                                \
    __builtin_amdgcn_s_barrier();                                                     \
    __builtin_amdgcn_sched_barrier(0);                                                \
  } while (0)

  // ---------------- main loop: tiles 0..30 computed here, 31 in tail ----------------
  for (int k = 0; k < 30; k += 2) {
    ITER(k, avA);
    ITER(k + 1, avB);
  }
  ITER(30, avA);
#undef ITER

  // keep the tail prefetches alive so the vmcnt discipline is not broken by DCE
  asm volatile("" :: "v"(avA[0].x), "v"(avA[1].x), "v"(avA[2].x),
                     "v"(avB[0].x), "v"(avB[1].x), "v"(avB[2].x));

  // tail: compute tile 31 from buffer 1
  {
    const __hip_bfloat16* Ab = As + 6144;
    const __hip_bfloat16* Bb = Bs + 16384;
#pragma unroll
    for (int ks = 0; ks < 2; ++ks) {
      bhalf8 af[3], bf[4];
#pragma unroll
      for (int i = 0; i < 3; ++i) af[i] = *(const bhalf8*)(Ab + rAo[ks][i]);
#pragma unroll
      for (int j = 0; j < 4; ++j) bf[j] = *(const bhalf8*)(Bb + rBo[ks][j]);
#pragma unroll
      for (int i = 0; i < 3; ++i)
#pragma unroll
        for (int j = 0; j < 4; ++j)
          acc[i][j] = __builtin_amdgcn_mfma_f32_16x16x32_bf16(af[i], bf[j], acc[i][j], 0, 0, 0);
    }
  }

  // epilogue: C/D layout col = lane&15, row = q*4 + reg
  float bv[4];
#pragma unroll
  for (int j = 0; j < 4; ++j) bv[j] = bias[e * D_SZ + wn * 64 + j * 16 + l15];

#pragma unroll
  for (int i = 0; i < 3; ++i) {
#pragma unroll
    for (int r = 0; r < 4; ++r) {
      int gm = mbase + wm * 48 + i * 16 + q * 4 + r;
      if (gm < count) {
        int row = permE[gm];
        float* po = out + (size_t)row * D_SZ + wn * 64;
#pragma unroll
        for (int j = 0; j < 4; ++j) po[j * 16 + l15] = acc[i][j][r] + bv[j];
      }
    }
  }
}

extern "C" void kernel_launch(void* const* d_in, const int* in_sizes, int n_in,
                              void* d_out, int out_size, void* d_ws, size_t ws_size,
                              hipStream_t stream) {
  const float* x = (const float*)d_in[0];
  const float* W = (const float*)d_in[1];
  const float* bias = (const float*)d_in[2];
  const int* ids = (const int*)d_in[3];
  float* out = (float*)d_out;

  char* ws = (char*)d_ws;
  int* counts = (int*)ws;                                 // 32 B
  int* perm = (int*)(ws + 256);                           // 512 KB
  __hip_bfloat16* Wt = (__hip_bfloat16*)(ws + (1 << 20)); // 8 MB

  hipMemsetAsync(counts, 0, E_SZ * sizeof(int), stream);
  k_scatter<<<B_SZ / 256, 256, 0, stream>>>(ids, counts, perm);
  k_transpose<<<dim3(F_SZ / 64, D_SZ / 64, E_SZ), 256, 0, stream>>>(W, Wt);
  k_gemm<<<GRID_G, 512, 0, stream>>>(x, Wt, bias, counts, perm, out);
}